// Round 9
// baseline (303.689 us; speedup 1.0000x reference)
//
#include <hip/hip_runtime.h>
#include <hip/hip_bf16.h>
#include <math.h>
#include <stdint.h>

// Problem constants (fixed by the reference).
constexpr int Bz = 2;
constexpr int S  = 2048;
constexpr int E  = 1024;
constexpr int NH = 16;
constexpr int DH = 64;
constexpr int QS = 6144;        // combined qkv row stride: [g q|k|v | l q|k|v]

typedef __attribute__((ext_vector_type(8))) short short8;      // MFMA A/B frag (8 bf16)
typedef __attribute__((ext_vector_type(4))) float f32x4;       // MFMA C/D frag
typedef __attribute__((ext_vector_type(8))) unsigned short bf16x8;
typedef __attribute__((ext_vector_type(4))) unsigned short bf16x4;

__device__ __forceinline__ float bf2f(unsigned short u) {
    union { unsigned int i; float f; } c; c.i = ((unsigned int)u) << 16; return c.f;
}
__device__ __forceinline__ unsigned short f2bf(float f) {   // round-to-nearest-even
    union { float f; unsigned int i; } c; c.f = f;
    unsigned int r = c.i + 0x7fffu + ((c.i >> 16) & 1u);
    return (unsigned short)(r >> 16);
}

// 4x f32 -> packed bf16x4 store (hot path: HW pack if available).
__device__ __forceinline__ void pack4_store(unsigned short* dst,
                                            float a, float b, float c, float d) {
#if __has_builtin(__builtin_amdgcn_cvt_pk_bf16_f32)
    auto p0 = __builtin_amdgcn_cvt_pk_bf16_f32(a, b);
    auto p1 = __builtin_amdgcn_cvt_pk_bf16_f32(c, d);
    union { decltype(p0) v; unsigned int u; } c0, c1;
    c0.v = p0; c1.v = p1;
    uint2 w; w.x = c0.u; w.y = c1.u;
    *(uint2*)dst = w;
#else
    bf16x4 o = { f2bf(a), f2bf(b), f2bf(c), f2bf(d) };
    *(bf16x4*)dst = o;
#endif
}

#define GLD_LDS(g, l) __builtin_amdgcn_global_load_lds( \
    (const __attribute__((address_space(1))) void*)(g), \
    (__attribute__((address_space(3))) void*)(l), 16, 0, 0)

// ---------------------------------------------------------------------------
// prep_all — one launch for all preprocessing:
//   blocks [0, 12288)      : fp32->bf16 cvt of {x, w_in_g, w_in_l, w_f}
//   blocks [12288, 12800)  : transpose-convert w_out_g/l -> bf16 woutT
//   blocks [12800, 13056)  : cb[n] = b_f + wf[:, :1024]@bog + wf[:, 1024:]@bol
// ---------------------------------------------------------------------------
struct PrepArgs {
    const float* csrc[4]; unsigned short* cdst[4]; int cn[4];
    const float* wog; const float* wol;
    unsigned short* wogT; unsigned short* wolT;
    const float* wf; const float* bf; const float* bog; const float* bol;
    float* cb;
};

__global__ __launch_bounds__(256)
void prep_all(PrepArgs a)
{
    __shared__ unsigned short T[64][72];
    const int bid = blockIdx.x, t = threadIdx.x;

    if (bid < 12288) {                      // ---- cvt path
        int i = (bid * 256 + t) * 4;
        #pragma unroll
        for (int r = 0; r < 4; ++r) {
            if (i < a.cn[r]) {
                float4 v = *(const float4*)(a.csrc[r] + i);
                bf16x4 o = { f2bf(v.x), f2bf(v.y), f2bf(v.z), f2bf(v.w) };
                *(bf16x4*)(a.cdst[r] + i) = o;
                return;
            }
            i -= a.cn[r];
        }
        return;
    }
    if (bid < 12800) {                      // ---- transpose-convert path
        const int id = bid - 12288;
        const int tj = id & 15, ti = (id >> 4) & 15, mat = id >> 8;
        const float* src = mat ? a.wol : a.wog;
        unsigned short* dst = mat ? a.wolT : a.wogT;
        #pragma unroll
        for (int r = 0; r < 4; ++r) {
            const int c = r * 256 + t;
            const int row = c >> 4, col4 = (c & 15) * 4;
            float4 v = *(const float4*)(src + (size_t)(ti * 64 + row) * 1024 + tj * 64 + col4);
            T[col4 + 0][row] = f2bf(v.x);
            T[col4 + 1][row] = f2bf(v.y);
            T[col4 + 2][row] = f2bf(v.z);
            T[col4 + 3][row] = f2bf(v.w);
        }
        __syncthreads();
        #pragma unroll
        for (int r = 0; r < 2; ++r) {
            const int c = r * 256 + t;
            const int jrow = c >> 3, ig = (c & 7) * 8;
            bf16x8 o;
            #pragma unroll
            for (int k = 0; k < 8; ++k) o[k] = T[jrow][ig + k];
            *(bf16x8*)(dst + (size_t)(tj * 64 + jrow) * 1024 + ti * 64 + ig) = o;
        }
        return;
    }
    {                                       // ---- combined-bias path
        const int lane = t & 63;
        const int n = (bid - 12800) * 4 + (t >> 6);
        const float* row = a.wf + (size_t)n * 2048;
        float s = 0.f;
        #pragma unroll
        for (int i = 0; i < 16; ++i) s = fmaf(row[i * 64 + lane], a.bog[i * 64 + lane], s);
        #pragma unroll
        for (int i = 16; i < 32; ++i) s = fmaf(row[i * 64 + lane], a.bol[i * 64 + lane - 1024], s);
        #pragma unroll
        for (int off = 32; off > 0; off >>= 1) s += __shfl_xor(s, off, 64);
        if (lane == 0) a.cb[n] = a.bf[n] + s;
    }
}

// ---------------------------------------------------------------------------
// gemm_fused — one launch for BOTH K=1024 GEMMs:
//   blocks [0, 1536)   : QKV  [4096,6144] = xb @ win_all^T (+bias, +fused
//                        V-transposes)  — bk64 128x128.
//   blocks [1536,1664) : wcomb_z [1024,1024@z] = wf_b[:,z*1024:] @ woutT_z^T.
// V-range columns of qkv (nn in [2048,3072) u [5120,6144)) are dead in C
// (read via vt/vtl only) — C stores skipped.
// ---------------------------------------------------------------------------
struct GemmFusedArgs {
    const unsigned short* xb;    const unsigned short* win;
    const unsigned short* wfb;   const unsigned short* woutT;
    const float* bg;             const float* bl;
    unsigned short* qkv;  unsigned short* vt;  unsigned short* vtl;
    unsigned short* wcomb;
};

__global__ __launch_bounds__(256, 2)
void gemm_fused(GemmFusedArgs g)
{
    __shared__ __align__(16) short As[128 * 64];   // 16 KB
    __shared__ __align__(16) short Bs[128 * 64];   // 16 KB

    const int bid = blockIdx.x;
    const unsigned short *A, *W;
    unsigned short *C, *vt, *vtl;
    const float *bias0, *bias1;
    int m0, n0, lda, ldw, ldc, nsplit;

    if (bid < 1536) {                       // ---- QKV branch
        m0 = (bid / 48) * 128;  n0 = (bid % 48) * 128;
        A = g.xb;  W = g.win;  C = g.qkv;  vt = g.vt;  vtl = g.vtl;
        bias0 = g.bg;  bias1 = g.bl;
        lda = 1024;  ldw = 1024;  ldc = QS;  nsplit = 3072;
    } else {                                // ---- wcomb branch
        const int id = bid - 1536;
        const int z = id >> 6;
        m0 = ((id >> 3) & 7) * 128;  n0 = (id & 7) * 128;
        A = g.wfb + z * 1024;
        W = g.woutT + (size_t)z * 1024 * 1024;
        C = g.wcomb + z * 1024;
        vt = nullptr;  vtl = nullptr;  bias0 = nullptr;  bias1 = nullptr;
        lda = 2048;  ldw = 1024;  ldc = 2048;  nsplit = 0;
    }

    const int t = threadIdx.x;
    const int lane = t & 63, wave = t >> 6;
    const int wm = wave & 1, wn = wave >> 1;
    const int lm = lane & 15, lk = lane >> 4;

    f32x4 acc[4][4] = {};

    const int row0 = t >> 3, kg0 = (t & 7) * 8;
    const unsigned short* a0 = A + (size_t)(m0 + row0) * lda + kg0;
    const unsigned short* w0 = W + (size_t)(n0 + row0) * ldw + kg0;

    for (int k0 = 0; k0 < 1024; k0 += 64) {
        __syncthreads();
        #pragma unroll
        for (int r = 0; r < 4; ++r)
            GLD_LDS(a0 + (size_t)(r * 32) * lda + k0, As + ((size_t)(r * 256 + wave * 64)) * 8);
        #pragma unroll
        for (int r = 0; r < 4; ++r)
            GLD_LDS(w0 + (size_t)(r * 32) * ldw + k0, Bs + ((size_t)(r * 256 + wave * 64)) * 8);
        __syncthreads();

        #pragma unroll
        for (int ks = 0; ks < 2; ++ks) {
            short8 af[4], bfr[4];
            #pragma unroll
            for (int i = 0; i < 4; ++i)
                af[i] = *(const short8*)&As[(wm * 64 + i * 16 + lm) * 64 + ks * 32 + lk * 8];
            #pragma unroll
            for (int j = 0; j < 4; ++j)
                bfr[j] = *(const short8*)&Bs[(wn * 64 + j * 16 + lm) * 64 + ks * 32 + lk * 8];
            #pragma unroll
            for (int i = 0; i < 4; ++i)
                #pragma unroll
                for (int j = 0; j < 4; ++j)
                    acc[i][j] = __builtin_amdgcn_mfma_f32_16x16x32_bf16(af[i], bfr[j], acc[i][j], 0, 0, 0);
        }
    }

    #pragma unroll
    for (int i = 0; i < 4; ++i) {
        #pragma unroll
        for (int j = 0; j < 4; ++j) {
            const int nn = n0 + wn * 64 + j * 16 + lm;
            const float bv = (nn < nsplit) ? (bias0 ? bias0[nn] : 0.f)
                                           : (bias1 ? bias1[nn - nsplit] : 0.f);
            const int mm0 = m0 + wm * 64 + i * 16 + lk * 4;
            float vv[4];
            // V columns are dead in C (read via vt/vtl only) — skip the store.
            const bool deadC = vt && ((nn >= 2048 && nn < 3072) || nn >= 5120);
            #pragma unroll
            for (int r = 0; r < 4; ++r) {
                vv[r] = acc[i][j][r] + bv;
                if (!deadC) C[(size_t)(mm0 + r) * ldc + nn] = f2bf(vv[r]);
            }
            if (vt) {
                const int nl = nn - 2048;              // V-range of global half
                if (nl >= 0 && nl < 1024) {
                    const int hh = nl >> 6, dd = nl & 63;
                    const int bb = mm0 >> 11, ss = mm0 & 2047;
                    pack4_store(vt + ((size_t)(bb * NH + hh) * 64 + dd) * S + ss,
                                vv[0], vv[1], vv[2], vv[3]);
                }
                const int nl2 = nn - 5120;             // V-range of local half
                if (nl2 >= 0) {
                    const int hh = nl2 >> 6, dd = nl2 & 63;
                    const int bb = mm0 >> 11, ss = mm0 & 2047;
                    pack4_store(vtl + ((size_t)(bb * NH + hh) * 64 + dd) * S + ss,
                                vv[0], vv[1], vv[2], vv[3]);
                }
            }
        }
    }
}

// ---------------------------------------------------------------------------
// gemm_tail — 128x64 tile, BK=64 (tail: [4096,1024] = attn_cat @ wcomb^T + cb,
// fp32 out). 512 blocks at 2/CU = one full round.
// ---------------------------------------------------------------------------
__global__ __launch_bounds__(256, 2)
void gemm_tail(const unsigned short* __restrict__ A, const unsigned short* __restrict__ W,
               const float* __restrict__ bias, float* __restrict__ C)
{
    __shared__ __align__(16) short As[128 * 64];   // 16 KB
    __shared__ __align__(16) short Bs[64 * 64];    //  8 KB

    const int t = threadIdx.x;
    const int lane = t & 63, wave = t >> 6;
    const int wm = wave & 1, wn = wave >> 1;       // 2M x 2N wave grid
    const int m0 = blockIdx.y * 128, n0 = blockIdx.x * 64;
    const int lm = lane & 15, lk = lane >> 4;

    f32x4 acc[4][2] = {};

    const int row0 = t >> 3, kg0 = (t & 7) * 8;
    const unsigned short* a0 = A + (size_t)(m0 + row0) * 2048 + kg0;
    const unsigned short* w0 = W + (size_t)(n0 + row0) * 2048 + kg0;

    for (int k0 = 0; k0 < 2048; k0 += 64) {
        __syncthreads();
        #pragma unroll
        for (int r = 0; r < 4; ++r)
            GLD_LDS(a0 + (size_t)(r * 32) * 2048 + k0, As + ((size_t)(r * 256 + wave * 64)) * 8);
        #pragma unroll
        for (int r = 0; r < 2; ++r)
            GLD_LDS(w0 + (size_t)(r * 32) * 2048 + k0, Bs + ((size_t)(r * 256 + wave * 64)) * 8);
        __syncthreads();

        #pragma unroll
        for (int ks = 0; ks < 2; ++ks) {
            short8 af[4], bfr[2];
            #pragma unroll
            for (int i = 0; i < 4; ++i)
                af[i] = *(const short8*)&As[(wm * 64 + i * 16 + lm) * 64 + ks * 32 + lk * 8];
            #pragma unroll
            for (int j = 0; j < 2; ++j)
                bfr[j] = *(const short8*)&Bs[(wn * 32 + j * 16 + lm) * 64 + ks * 32 + lk * 8];
            #pragma unroll
            for (int i = 0; i < 4; ++i)
                #pragma unroll
                for (int j = 0; j < 2; ++j)
                    acc[i][j] = __builtin_amdgcn_mfma_f32_16x16x32_bf16(af[i], bfr[j], acc[i][j], 0, 0, 0);
        }
    }

    #pragma unroll
    for (int i = 0; i < 4; ++i) {
        #pragma unroll
        for (int j = 0; j < 2; ++j) {
            const int nn = n0 + wn * 32 + j * 16 + lm;
            const float bv = bias[nn];
            const int mm0 = m0 + wm * 64 + i * 16 + lk * 4;
            #pragma unroll
            for (int r = 0; r < 4; ++r)
                C[(size_t)(mm0 + r) * 1024 + nn] = acc[i][j][r] + bv;
        }
    }
}

// ---------------------------------------------------------------------------
// attn_fused — one launch for both attention flavors:
//   blocks [0, 256)    : global flash attention, NSPLIT=1, XCD-chunked remap.
//     R9: QBLK=256/block (4 waves x 64 queries, qg=4) — K/V fragment reads
//     amortize over 4 query-groups instead of 2: per-work LDS reads drop
//     40 -> 24 b128 (the flash loop is LDS-pipe-bound: 20rd+8wr vs 36 MFMA).
//     K-frags hoisted to registers once per iter. 2-phase K/V double-buffer
//     kept from R8; launch_bounds back to (256,2) (the (256,3) cap was R8's
//     regression suspect, mirroring R2's GEMM MINW=3 result). LDS 64 KB.
//   blocks [256, 1280) : block-local MFMA attention (writes local half).
// ---------------------------------------------------------------------------
__global__ __launch_bounds__(256, 2)
void attn_fused(const unsigned short* __restrict__ qkv,
                const unsigned short* __restrict__ vt,
                const unsigned short* __restrict__ vtl,
                unsigned short* __restrict__ attn)
{
    __shared__ __align__(16) unsigned short Ks[2][2][64][32];  // [db][kk] 16 KB
    __shared__ __align__(16) unsigned short Vs[2][2][64][32];  // 16 KB
    __shared__ __align__(16) unsigned short Pt[4][4][16][64];  // [wq][qg] 32 KB

    const int t = threadIdx.x, lane = t & 63, wq = t >> 6;
    const int lm = lane & 15, lk = lane >> 4;

    if (blockIdx.x < 256) {
        // =================== global flash path ===================
        // XCD-chunked decode: xcd = bid&7 owns 4 (b,h) pairs x 8 qb (bijective).
        const int bid = blockIdx.x;
        const int slot = bid >> 3;             // 0..31
        const int p  = (bid & 7) * 4 + (slot >> 3);
        const int qb = slot & 7;               // 0..7
        const int h  = p & 15;
        const int b  = p >> 4;
        const int q0 = qb * 256 + wq * 64;     // wave's first query (64 per wave)

        constexpr float QSCALE = 0.125f * 1.44269504088896340736f;
        short8 qf[4][2];
        #pragma unroll
        for (int qg = 0; qg < 4; ++qg) {
            const unsigned short* qrow = qkv + ((size_t)(b * S) + q0 + qg * 16 + lm) * QS + h * DH;
            #pragma unroll
            for (int kk = 0; kk < 2; ++kk) {
                bf16x8 v = *(const bf16x8*)(qrow + kk * 32 + lk * 8);
                #pragma unroll
                for (int j = 0; j < 8; ++j)
                    ((unsigned short*)&qf[qg][kk])[j] = f2bf(bf2f(v[j]) * QSCALE);
            }
        }

        short8 ones;                          // bf16 1.0 per element
        #pragma unroll
        for (int j = 0; j < 8; ++j) ((unsigned short*)&ones)[j] = 0x3F80;

        const int row0 = t >> 2;
        const int sw0 = (row0 ^ (row0 >> 2)) & 3;
        const int g0 = ((t & 3) ^ sw0) * 8;
        const unsigned short* kg[2];
        const unsigned short* vg[2];
        #pragma unroll
        for (int r = 0; r < 2; ++r) {
            kg[r] = qkv + ((size_t)(b * S) + row0) * QS + E + h * 64 + r * 32 + g0;
            vg[r] = vt + ((size_t)(b * NH + h) * 64 + row0) * S + r * 32 + g0;
        }

        f32x4 O[4][4] = {};
        f32x4 lacc[4] = {};
        const int sw = lm & 7;
        const int fr = (lm ^ (lm >> 2)) & 3;

        // ---- prologue: stage tile 0 into db=0.
        {
            GLD_LDS(kg[0], &Ks[0][0][0][0] + wq * 512);
            GLD_LDS(kg[1], &Ks[0][1][0][0] + wq * 512);
            GLD_LDS(vg[0], &Vs[0][0][0][0] + wq * 512);
            GLD_LDS(vg[1], &Vs[0][1][0][0] + wq * 512);
        }
        __syncthreads();

        for (int kt = 0; kt < 32; ++kt) {
            const int db = kt & 1;
            // ---- issue next tile's staging BEFORE compute (2-phase).
            if (kt + 1 < 32) {
                const int sb = db ^ 1;
                GLD_LDS(kg[0] + (size_t)(kt + 1) * 64 * QS, &Ks[sb][0][0][0] + wq * 512);
                GLD_LDS(kg[1] + (size_t)(kt + 1) * 64 * QS, &Ks[sb][1][0][0] + wq * 512);
                GLD_LDS(vg[0] + (kt + 1) * 64,              &Vs[sb][0][0][0] + wq * 512);
                GLD_LDS(vg[1] + (kt + 1) * 64,              &Vs[sb][1][0][0] + wq * 512);
            }

            // ---- K fragments once per iter (8 b128), reused by all 4 qg.
            short8 kfr[4][2];
            #pragma unroll
            for (int jn = 0; jn < 4; ++jn)
                #pragma unroll
                for (int kk = 0; kk < 2; ++kk)
                    kfr[jn][kk] = *(const short8*)&Ks[db][kk][jn * 16 + lm][(lk ^ fr) * 8];

            // ---- per-qg: S^T = K Q^T - 16, exp2, pack, read back P-frag.
            short8 pf[4][2];
            #pragma unroll
            for (int qg = 0; qg < 4; ++qg) {
                f32x4 stq[4];
                #pragma unroll
                for (int jn = 0; jn < 4; ++jn)
                    stq[jn] = (f32x4){ -16.f, -16.f, -16.f, -16.f };
                #pragma unroll
                for (int jn = 0; jn < 4; ++jn)
                    #pragma unroll
                    for (int kk = 0; kk < 2; ++kk)
                        stq[jn] = __builtin_amdgcn_mfma_f32_16x16x32_bf16(kfr[jn][kk], qf[qg][kk], stq[jn], 0, 0, 0);
                #pragma unroll
                for (int jn = 0; jn < 4; ++jn) {
                    const int cc = ((jn * 2 + (lk >> 1)) ^ sw) * 8 + (lk & 1) * 4;
                    pack4_store(&Pt[wq][qg][lm][cc],
                                exp2f(stq[jn][0]), exp2f(stq[jn][1]),
                                exp2f(stq[jn][2]), exp2f(stq[jn][3]));
                }
                pf[qg][0] = *(const short8*)&Pt[wq][qg][lm][((lk + 0) ^ sw) * 8];
                pf[qg][1] = *(const short8*)&Pt[wq][qg][lm][((lk + 4) ^ sw) * 8];
            }

            // ---- l += ones-row MFMA: 8 MFMA.
            #pragma unroll
            for (int qg = 0; qg < 4; ++qg)
                #pragma unroll
                for (int kk = 0; kk < 2; ++kk)
                    lacc[qg] = __builtin_amdgcn_mfma_f32_16x16x32_bf16(ones, pf[qg][kk], lacc[qg], 0, 0, 0);

            // ---- O^T += V^T P^T : 32 MFMA (V-frags reused by 4 qg).
            #pragma unroll
            for (int jd = 0; jd < 4; ++jd) {
                #pragma unroll
                for (int kk = 0; kk < 2; ++kk) {
                    short8 vf = *(const short8*)&Vs[db][kk][jd * 16 + lm][(lk ^ fr) * 8];
                    #pragma unroll
                    for (int qg = 0; qg < 4; ++qg)
                        O[qg][jd] = __builtin_amdgcn_mfma_f32_16x16x32_bf16(vf, pf[qg][kk], O[qg][jd], 0, 0, 0);
                }
            }

            // ---- single barrier/iter: drains staging (issued pre-compute)
            //      and publishes buf db^1 for the next iteration.
            if (kt + 1 < 32) __syncthreads();
        }

        // epilogue: normalized O directly to attn_cat global half.
        #pragma unroll
        for (int qg = 0; qg < 4; ++qg) {
            const int q = q0 + qg * 16 + lm;
            const float inv = 1.0f / lacc[qg][0];
            unsigned short* dst = attn + ((size_t)(b * S) + q) * 2048 + h * 64 + lk * 4;
            #pragma unroll
            for (int jd = 0; jd < 4; ++jd)
                pack4_store(dst + jd * 16,
                            O[qg][jd][0] * inv, O[qg][jd][1] * inv,
                            O[qg][jd][2] * inv, O[qg][jd][3] * inv);
        }
        return;
    }

    // =================== block-local path ===================
    // One wave per (b, 16-query block, head). Reuses Pt's first 4 KB.
    unsigned short (*PtL)[16][32] = (unsigned short(*)[16][32])&Pt[0][0][0][0];
    const unsigned short* qkvl = qkv + 3072;
    const int gid = (blockIdx.x - 256) * 4 + wq;   // b*2048 + sub*16 + h
    const int h   = gid & 15;
    const int sub = (gid >> 4) & 127;
    const int b   = gid >> 11;
    const int s0  = sub * 16;

    // ---- QK^T (K rows as A, Q rows as B; both lane-row = lm).
    const unsigned short* base = qkvl + ((size_t)(b * S) + s0 + lm) * QS;
    f32x4 st = {};
    #pragma unroll
    for (int kk = 0; kk < 2; ++kk) {
        short8 kf = *(const short8*)(base + E + h * 64 + kk * 32 + lk * 8);
        short8 qf = *(const short8*)(base +     h * 64 + kk * 32 + lk * 8);
        st = __builtin_amdgcn_mfma_f32_16x16x32_bf16(kf, qf, st, 0, 0, 0);
    }

    // ---- softmax over 16 keys (4 in-lane + 2 shfl hops across lk).
    constexpr float SC = 0.125f * 1.44269504088896340736f;   // dh^-0.5 * log2(e)
    float tt[4];
    #pragma unroll
    for (int r = 0; r < 4; ++r) tt[r] = st[r] * SC;
    float mx = fmaxf(fmaxf(tt[0], tt[1]), fmaxf(tt[2], tt[3]));
    mx = fmaxf(mx, __shfl_xor(mx, 16, 64));
    mx = fmaxf(mx, __shfl_xor(mx, 32, 64));
    float p[4], l = 0.f;
    #pragma unroll
    for (int r = 0; r < 4; ++r) { p[r] = exp2f(tt[r] - mx); l += p[r]; }
    l += __shfl_xor(l, 16, 64);
    l += __shfl_xor(l, 32, 64);
    const float inv = 1.0f / l;

    // ---- pack P^T to wave-private LDS (zero-padded to K=32).
    pack4_store(&PtL[wq][lm][lk * 4], p[0], p[1], p[2], p[3]);
    pack4_store(&PtL[wq][lm][16 + lk * 4], 0.f, 0.f, 0.f, 0.f);
    short8 pf = *(const short8*)&PtL[wq][lm][lk * 8];

    // ---- PV: O^T = V^T P^T (4 MFMA over d-blocks).
    const unsigned short* vrow =
        vtl + (((size_t)(b * NH + h) * 64) + lm) * S + s0 + (lk & 1) * 8;
    f32x4 zero = {};
    unsigned short* dst = attn + ((size_t)(b * S) + s0 + lm) * 2048 + 1024 + h * 64 + lk * 4;
    #pragma unroll
    for (int jd = 0; jd < 4; ++jd) {
        short8 vf = *(const short8*)(vrow + (size_t)jd * 16 * S);
        f32x4 O = __builtin_amdgcn_mfma_f32_16x16x32_bf16(vf, pf, zero, 0, 0, 0);
        pack4_store(dst + jd * 16, O[0] * inv, O[1] * inv, O[2] * inv, O[3] * inv);
    }
}

// ---------------------------------------------------------------------------
extern "C" void kernel_launch(void* const* d_in, const int* in_sizes, int n_in,
                              void* d_out, int out_size, void* d_ws, size_t ws_size,
                              hipStream_t stream)
{
    const float* x       = (const float*)d_in[0];
    const float* w_in_g  = (const float*)d_in[1];
    const float* b_in_g  = (const float*)d_in[2];
    const float* w_out_g = (const float*)d_in[3];
    const float* b_out_g = (const float*)d_in[4];
    const float* w_in_l  = (const float*)d_in[5];
    const float* b_in_l  = (const float*)d_in[6];
    const float* w_out_l = (const float*)d_in[7];
    const float* b_out_l = (const float*)d_in[8];
    const float* w_f     = (const float*)d_in[9];
    const float* b_f     = (const float*)d_in[10];
    float* out = (float*)d_out;

    const int M = Bz * S;   // 4096
    char* p = (char*)d_ws;
    unsigned short* xb       = (unsigned short*)p; p += (size_t)M * 1024 * 2;        //  8 MB
    unsigned short* qkv_all  = (unsigned short*)p; p += (size_t)M * QS * 2;          // 48 MB
    unsigned short* attn_cat = (unsigned short*)p; p += (size_t)M * 2048 * 2;        // 16 MB
    unsigned short* win_all  = (unsigned short*)p; p += (size_t)6144 * 1024 * 2;     // 12 MB
    unsigned short* wf_b     = (unsigned short*)p; p += (size_t)1024 * 2048 * 2;     //  4 MB
    unsigned short* woutT    = (unsigned short*)p; p += (size_t)2 * 1024 * 1024 * 2; //  4 MB
    unsigned short* wcomb    = (unsigned short*)p; p += (size_t)1024 * 2048 * 2;     //  4 MB
    unsigned short* vtbuf    = (unsigned short*)p; p += (size_t)Bz * NH * 64 * S * 2;//  8 MB
    unsigned short* vtlbuf   = (unsigned short*)p; p += (size_t)Bz * NH * 64 * S * 2;//  8 MB
    float*          cb       = (float*)p;          p += 1024 * 4;

    dim3 blk(256);

    // 1) all preprocessing in one launch.
    PrepArgs pa;
    pa.csrc[0] = x;      pa.cdst[0] = xb;                    pa.cn[0] = M * 1024;
    pa.csrc[1] = w_in_g; pa.cdst[1] = win_all;               pa.cn[1] = 3072 * 1024;
    pa.csrc[2] = w_in_l; pa.cdst[2] = win_all + 3072 * 1024; pa.cn[2] = 3072 * 1024;
    pa.csrc[3] = w_f;    pa.cdst[3] = wf_b;                  pa.cn[3] = 1024 * 2048;
    pa.wog = w_out_g; pa.wol = w_out_l;
    pa.wogT = woutT;  pa.wolT = woutT + 1024 * 1024;
    pa.wf = w_f; pa.bf = b_f; pa.bog = b_out_g; pa.bol = b_out_l; pa.cb = cb;
    prep_all<<<dim3(13056), blk, 0, stream>>>(pa);

    // 2) QKV GEMM + wcomb GEMM in ONE launch (1536 + 128 blocks).
    GemmFusedArgs ga;
    ga.xb = xb;  ga.win = win_all;  ga.wfb = wf_b;  ga.woutT = woutT;
    ga.bg = b_in_g;  ga.bl = b_in_l;
    ga.qkv = qkv_all;  ga.vt = vtbuf;  ga.vtl = vtlbuf;  ga.wcomb = wcomb;
    gemm_fused<<<dim3(1664), blk, 0, stream>>>(ga);

    // 3) global flash (QBLK=256, 2-phase) + local attention in ONE launch.
    attn_fused<<<dim3(1280), blk, 0, stream>>>(qkv_all, vtbuf, vtlbuf, attn_cat);

    // 4) Fused tail: out = attn_cat [4096,2048] @ wcomb[1024,2048]^T + cb (fp32).
    gemm_tail<<<dim3(1024 / 64, M / 128), blk, 0, stream>>>(
        attn_cat, wcomb, cb, out);
}

// Round 10
// 293.165 us; speedup vs baseline: 1.0359x; 1.0359x over previous
//
#include <hip/hip_runtime.h>
#include <hip/hip_bf16.h>
#include <math.h>
#include <stdint.h>

// Problem constants (fixed by the reference).
constexpr int Bz = 2;
constexpr int S  = 2048;
constexpr int E  = 1024;
constexpr int NH = 16;
constexpr int DH = 64;
constexpr int QS = 6144;        // combined qkv row stride: [g q|k|v | l q|k|v]
constexpr int NSPLIT = 2;       // key splits for global flash attention
constexpr int KT_SPLIT = (S / 64) / NSPLIT;   // 16 key-tiles per split

typedef __attribute__((ext_vector_type(8))) short short8;      // MFMA A/B frag (8 bf16)
typedef __attribute__((ext_vector_type(4))) float f32x4;       // MFMA C/D frag
typedef __attribute__((ext_vector_type(8))) unsigned short bf16x8;
typedef __attribute__((ext_vector_type(4))) unsigned short bf16x4;

__device__ __forceinline__ float bf2f(unsigned short u) {
    union { unsigned int i; float f; } c; c.i = ((unsigned int)u) << 16; return c.f;
}
__device__ __forceinline__ unsigned short f2bf(float f) {   // round-to-nearest-even
    union { float f; unsigned int i; } c; c.f = f;
    unsigned int r = c.i + 0x7fffu + ((c.i >> 16) & 1u);
    return (unsigned short)(r >> 16);
}

// 4x f32 -> packed bf16x4 store (hot path: HW pack if available).
__device__ __forceinline__ void pack4_store(unsigned short* dst,
                                            float a, float b, float c, float d) {
#if __has_builtin(__builtin_amdgcn_cvt_pk_bf16_f32)
    auto p0 = __builtin_amdgcn_cvt_pk_bf16_f32(a, b);
    auto p1 = __builtin_amdgcn_cvt_pk_bf16_f32(c, d);
    union { decltype(p0) v; unsigned int u; } c0, c1;
    c0.v = p0; c1.v = p1;
    uint2 w; w.x = c0.u; w.y = c1.u;
    *(uint2*)dst = w;
#else
    bf16x4 o = { f2bf(a), f2bf(b), f2bf(c), f2bf(d) };
    *(bf16x4*)dst = o;
#endif
}

#define GLD_LDS(g, l) __builtin_amdgcn_global_load_lds( \
    (const __attribute__((address_space(1))) void*)(g), \
    (__attribute__((address_space(3))) void*)(l), 16, 0, 0)

// ---------------------------------------------------------------------------
// prep_all — one launch for all preprocessing:
//   blocks [0, 12288)      : fp32->bf16 cvt of {x, w_in_g, w_in_l, w_f}
//   blocks [12288, 12800)  : transpose-convert w_out_g/l -> bf16 woutT
//   blocks [12800, 13056)  : cb[n] = b_f + wf[:, :1024]@bog + wf[:, 1024:]@bol
// ---------------------------------------------------------------------------
struct PrepArgs {
    const float* csrc[4]; unsigned short* cdst[4]; int cn[4];
    const float* wog; const float* wol;
    unsigned short* wogT; unsigned short* wolT;
    const float* wf; const float* bf; const float* bog; const float* bol;
    float* cb;
};

__global__ __launch_bounds__(256)
void prep_all(PrepArgs a)
{
    __shared__ unsigned short T[64][72];
    const int bid = blockIdx.x, t = threadIdx.x;

    if (bid < 12288) {                      // ---- cvt path
        int i = (bid * 256 + t) * 4;
        #pragma unroll
        for (int r = 0; r < 4; ++r) {
            if (i < a.cn[r]) {
                float4 v = *(const float4*)(a.csrc[r] + i);
                bf16x4 o = { f2bf(v.x), f2bf(v.y), f2bf(v.z), f2bf(v.w) };
                *(bf16x4*)(a.cdst[r] + i) = o;
                return;
            }
            i -= a.cn[r];
        }
        return;
    }
    if (bid < 12800) {                      // ---- transpose-convert path
        const int id = bid - 12288;
        const int tj = id & 15, ti = (id >> 4) & 15, mat = id >> 8;
        const float* src = mat ? a.wol : a.wog;
        unsigned short* dst = mat ? a.wolT : a.wogT;
        #pragma unroll
        for (int r = 0; r < 4; ++r) {
            const int c = r * 256 + t;
            const int row = c >> 4, col4 = (c & 15) * 4;
            float4 v = *(const float4*)(src + (size_t)(ti * 64 + row) * 1024 + tj * 64 + col4);
            T[col4 + 0][row] = f2bf(v.x);
            T[col4 + 1][row] = f2bf(v.y);
            T[col4 + 2][row] = f2bf(v.z);
            T[col4 + 3][row] = f2bf(v.w);
        }
        __syncthreads();
        #pragma unroll
        for (int r = 0; r < 2; ++r) {
            const int c = r * 256 + t;
            const int jrow = c >> 3, ig = (c & 7) * 8;
            bf16x8 o;
            #pragma unroll
            for (int k = 0; k < 8; ++k) o[k] = T[jrow][ig + k];
            *(bf16x8*)(dst + (size_t)(tj * 64 + jrow) * 1024 + ti * 64 + ig) = o;
        }
        return;
    }
    {                                       // ---- combined-bias path
        const int lane = t & 63;
        const int n = (bid - 12800) * 4 + (t >> 6);
        const float* row = a.wf + (size_t)n * 2048;
        float s = 0.f;
        #pragma unroll
        for (int i = 0; i < 16; ++i) s = fmaf(row[i * 64 + lane], a.bog[i * 64 + lane], s);
        #pragma unroll
        for (int i = 16; i < 32; ++i) s = fmaf(row[i * 64 + lane], a.bol[i * 64 + lane - 1024], s);
        #pragma unroll
        for (int off = 32; off > 0; off >>= 1) s += __shfl_xor(s, off, 64);
        if (lane == 0) a.cb[n] = a.bf[n] + s;
    }
}

// ---------------------------------------------------------------------------
// gemm_fused — one launch for BOTH K=1024 GEMMs:
//   blocks [0, 1536)   : QKV  [4096,6144] = xb @ win_all^T (+bias, +fused
//                        V-transposes)  — bk64 128x128.
//   blocks [1536,1664) : wcomb_z [1024,1024@z] = wf_b[:,z*1024:] @ woutT_z^T.
// V-range columns of qkv (nn in [2048,3072) u [5120,6144)) are dead in C
// (read via vt/vtl only) — C stores skipped.
// ---------------------------------------------------------------------------
struct GemmFusedArgs {
    const unsigned short* xb;    const unsigned short* win;
    const unsigned short* wfb;   const unsigned short* woutT;
    const float* bg;             const float* bl;
    unsigned short* qkv;  unsigned short* vt;  unsigned short* vtl;
    unsigned short* wcomb;
};

__global__ __launch_bounds__(256, 2)
void gemm_fused(GemmFusedArgs g)
{
    __shared__ __align__(16) short As[128 * 64];   // 16 KB
    __shared__ __align__(16) short Bs[128 * 64];   // 16 KB

    const int bid = blockIdx.x;
    const unsigned short *A, *W;
    unsigned short *C, *vt, *vtl;
    const float *bias0, *bias1;
    int m0, n0, lda, ldw, ldc, nsplit;

    if (bid < 1536) {                       // ---- QKV branch
        m0 = (bid / 48) * 128;  n0 = (bid % 48) * 128;
        A = g.xb;  W = g.win;  C = g.qkv;  vt = g.vt;  vtl = g.vtl;
        bias0 = g.bg;  bias1 = g.bl;
        lda = 1024;  ldw = 1024;  ldc = QS;  nsplit = 3072;
    } else {                                // ---- wcomb branch
        const int id = bid - 1536;
        const int z = id >> 6;
        m0 = ((id >> 3) & 7) * 128;  n0 = (id & 7) * 128;
        A = g.wfb + z * 1024;
        W = g.woutT + (size_t)z * 1024 * 1024;
        C = g.wcomb + z * 1024;
        vt = nullptr;  vtl = nullptr;  bias0 = nullptr;  bias1 = nullptr;
        lda = 2048;  ldw = 1024;  ldc = 2048;  nsplit = 0;
    }

    const int t = threadIdx.x;
    const int lane = t & 63, wave = t >> 6;
    const int wm = wave & 1, wn = wave >> 1;
    const int lm = lane & 15, lk = lane >> 4;

    f32x4 acc[4][4] = {};

    const int row0 = t >> 3, kg0 = (t & 7) * 8;
    const unsigned short* a0 = A + (size_t)(m0 + row0) * lda + kg0;
    const unsigned short* w0 = W + (size_t)(n0 + row0) * ldw + kg0;

    for (int k0 = 0; k0 < 1024; k0 += 64) {
        __syncthreads();
        #pragma unroll
        for (int r = 0; r < 4; ++r)
            GLD_LDS(a0 + (size_t)(r * 32) * lda + k0, As + ((size_t)(r * 256 + wave * 64)) * 8);
        #pragma unroll
        for (int r = 0; r < 4; ++r)
            GLD_LDS(w0 + (size_t)(r * 32) * ldw + k0, Bs + ((size_t)(r * 256 + wave * 64)) * 8);
        __syncthreads();

        #pragma unroll
        for (int ks = 0; ks < 2; ++ks) {
            short8 af[4], bfr[4];
            #pragma unroll
            for (int i = 0; i < 4; ++i)
                af[i] = *(const short8*)&As[(wm * 64 + i * 16 + lm) * 64 + ks * 32 + lk * 8];
            #pragma unroll
            for (int j = 0; j < 4; ++j)
                bfr[j] = *(const short8*)&Bs[(wn * 64 + j * 16 + lm) * 64 + ks * 32 + lk * 8];
            #pragma unroll
            for (int i = 0; i < 4; ++i)
                #pragma unroll
                for (int j = 0; j < 4; ++j)
                    acc[i][j] = __builtin_amdgcn_mfma_f32_16x16x32_bf16(af[i], bfr[j], acc[i][j], 0, 0, 0);
        }
    }

    #pragma unroll
    for (int i = 0; i < 4; ++i) {
        #pragma unroll
        for (int j = 0; j < 4; ++j) {
            const int nn = n0 + wn * 64 + j * 16 + lm;
            const float bv = (nn < nsplit) ? (bias0 ? bias0[nn] : 0.f)
                                           : (bias1 ? bias1[nn - nsplit] : 0.f);
            const int mm0 = m0 + wm * 64 + i * 16 + lk * 4;
            float vv[4];
            // V columns are dead in C (read via vt/vtl only) — skip the store.
            const bool deadC = vt && ((nn >= 2048 && nn < 3072) || nn >= 5120);
            #pragma unroll
            for (int r = 0; r < 4; ++r) {
                vv[r] = acc[i][j][r] + bv;
                if (!deadC) C[(size_t)(mm0 + r) * ldc + nn] = f2bf(vv[r]);
            }
            if (vt) {
                const int nl = nn - 2048;              // V-range of global half
                if (nl >= 0 && nl < 1024) {
                    const int hh = nl >> 6, dd = nl & 63;
                    const int bb = mm0 >> 11, ss = mm0 & 2047;
                    pack4_store(vt + ((size_t)(bb * NH + hh) * 64 + dd) * S + ss,
                                vv[0], vv[1], vv[2], vv[3]);
                }
                const int nl2 = nn - 5120;             // V-range of local half
                if (nl2 >= 0) {
                    const int hh = nl2 >> 6, dd = nl2 & 63;
                    const int bb = mm0 >> 11, ss = mm0 & 2047;
                    pack4_store(vtl + ((size_t)(bb * NH + hh) * 64 + dd) * S + ss,
                                vv[0], vv[1], vv[2], vv[3]);
                }
            }
        }
    }
}

// ---------------------------------------------------------------------------
// gemm_tail — 128x64 tile, BK=64 (tail: [4096,1024] = attn_cat @ wcomb^T + cb,
// fp32 out). 512 blocks at 2/CU = one full round.
// ---------------------------------------------------------------------------
__global__ __launch_bounds__(256, 2)
void gemm_tail(const unsigned short* __restrict__ A, const unsigned short* __restrict__ W,
               const float* __restrict__ bias, float* __restrict__ C)
{
    __shared__ __align__(16) short As[128 * 64];   // 16 KB
    __shared__ __align__(16) short Bs[64 * 64];    //  8 KB

    const int t = threadIdx.x;
    const int lane = t & 63, wave = t >> 6;
    const int wm = wave & 1, wn = wave >> 1;       // 2M x 2N wave grid
    const int m0 = blockIdx.y * 128, n0 = blockIdx.x * 64;
    const int lm = lane & 15, lk = lane >> 4;

    f32x4 acc[4][2] = {};

    const int row0 = t >> 3, kg0 = (t & 7) * 8;
    const unsigned short* a0 = A + (size_t)(m0 + row0) * 2048 + kg0;
    const unsigned short* w0 = W + (size_t)(n0 + row0) * 2048 + kg0;

    for (int k0 = 0; k0 < 2048; k0 += 64) {
        __syncthreads();
        #pragma unroll
        for (int r = 0; r < 4; ++r)
            GLD_LDS(a0 + (size_t)(r * 32) * 2048 + k0, As + ((size_t)(r * 256 + wave * 64)) * 8);
        #pragma unroll
        for (int r = 0; r < 2; ++r)
            GLD_LDS(w0 + (size_t)(r * 32) * 2048 + k0, Bs + ((size_t)(r * 256 + wave * 64)) * 8);
        __syncthreads();

        #pragma unroll
        for (int ks = 0; ks < 2; ++ks) {
            short8 af[4], bfr[2];
            #pragma unroll
            for (int i = 0; i < 4; ++i)
                af[i] = *(const short8*)&As[(wm * 64 + i * 16 + lm) * 64 + ks * 32 + lk * 8];
            #pragma unroll
            for (int j = 0; j < 2; ++j)
                bfr[j] = *(const short8*)&Bs[(wn * 32 + j * 16 + lm) * 64 + ks * 32 + lk * 8];
            #pragma unroll
            for (int i = 0; i < 4; ++i)
                #pragma unroll
                for (int j = 0; j < 2; ++j)
                    acc[i][j] = __builtin_amdgcn_mfma_f32_16x16x32_bf16(af[i], bfr[j], acc[i][j], 0, 0, 0);
        }
    }

    #pragma unroll
    for (int i = 0; i < 4; ++i) {
        #pragma unroll
        for (int j = 0; j < 2; ++j) {
            const int nn = n0 + wn * 32 + j * 16 + lm;
            const float bv = bias[nn];
            const int mm0 = m0 + wm * 64 + i * 16 + lk * 4;
            #pragma unroll
            for (int r = 0; r < 4; ++r)
                C[(size_t)(mm0 + r) * 1024 + nn] = acc[i][j][r] + bv;
        }
    }
}

// ---------------------------------------------------------------------------
// attn_fused — one launch for both attention flavors:
//   blocks [0, 1024)    : global flash attention, NSPLIT=2 split-K (round-0
//     verified body). R10 rationale: R9 counters showed the flash tail runs
//     at Occupancy 12% (1 wave/SIMD) with a long serial chain (VALUBusy 43%,
//     MfmaUtil 17%) — the lever is WAVES. Split-K doubles blocks to 1024 at
//     32 KB LDS (4-5 blocks/CU); fixed-max softmax makes the merge an exact
//     sum. Writes unnormalized opart (bf16) + lbuf (f32).
//   blocks [1024, 2048) : block-local MFMA attention (writes local half).
// ---------------------------------------------------------------------------
__global__ __launch_bounds__(256, 2)
void attn_fused(const unsigned short* __restrict__ qkv,
                const unsigned short* __restrict__ vt,
                const unsigned short* __restrict__ vtl,
                unsigned short* __restrict__ opart, float* __restrict__ lbuf,
                unsigned short* __restrict__ attn)
{
    __shared__ __align__(16) unsigned short Ks[2][64][32];    // 8 KB
    __shared__ __align__(16) unsigned short Vs[2][64][32];    // 8 KB
    __shared__ __align__(16) unsigned short Pt[4][2][16][64]; // 16 KB

    const int t = threadIdx.x, lane = t & 63, wq = t >> 6;
    const int lm = lane & 15, lk = lane >> 4;

    if (blockIdx.x < 1024) {
        // =================== global flash path (split-K) ===================
        const int bid = blockIdx.x;          // b*512 + h*32 + qb*2 + split
        const int split = bid & 1;
        const int qb = (bid >> 1) & 15;
        const int h  = (bid >> 5) & 15;
        const int b  = bid >> 9;
        const int q0 = qb * 128 + wq * 32;   // wave's first query

        constexpr float QSCALE = 0.125f * 1.44269504088896340736f;
        short8 qf[2][2];
        #pragma unroll
        for (int qg = 0; qg < 2; ++qg) {
            const unsigned short* qrow = qkv + ((size_t)(b * S) + q0 + qg * 16 + lm) * QS + h * DH;
            #pragma unroll
            for (int kk = 0; kk < 2; ++kk) {
                bf16x8 v = *(const bf16x8*)(qrow + kk * 32 + lk * 8);
                #pragma unroll
                for (int j = 0; j < 8; ++j)
                    ((unsigned short*)&qf[qg][kk])[j] = f2bf(bf2f(v[j]) * QSCALE);
            }
        }

        short8 ones;                          // bf16 1.0 per element
        #pragma unroll
        for (int j = 0; j < 8; ++j) ((unsigned short*)&ones)[j] = 0x3F80;

        const int row0 = t >> 2;
        const int sw0 = (row0 ^ (row0 >> 2)) & 3;
        const int g0 = ((t & 3) ^ sw0) * 8;
        const unsigned short* kg[2];
        const unsigned short* vg[2];
        #pragma unroll
        for (int r = 0; r < 2; ++r) {
            kg[r] = qkv + ((size_t)(b * S) + row0) * QS + E + h * 64 + r * 32 + g0;
            vg[r] = vt + ((size_t)(b * NH + h) * 64 + row0) * S + r * 32 + g0;
        }
        unsigned short* kl[2] = { &Ks[0][0][0] + (wq * 64) * 8, &Ks[0][0][0] + (256 + wq * 64) * 8 };
        unsigned short* vl[2] = { &Vs[0][0][0] + (wq * 64) * 8, &Vs[0][0][0] + (256 + wq * 64) * 8 };

        f32x4 O[2][4] = {};
        f32x4 lacc[2] = {};
        const int sw = lm & 7;
        const int fr = (lm ^ (lm >> 2)) & 3;

        for (int kt = split * KT_SPLIT; kt < (split + 1) * KT_SPLIT; ++kt) {
            __syncthreads();
            GLD_LDS(kg[0] + (size_t)kt * 64 * QS, kl[0]);
            GLD_LDS(kg[1] + (size_t)kt * 64 * QS, kl[1]);
            GLD_LDS(vg[0] + kt * 64, vl[0]);
            GLD_LDS(vg[1] + kt * 64, vl[1]);
            __syncthreads();

            // S^T = K Q^T - 16 (fixed-max shift via C-init): 16 MFMA.
            f32x4 st[2][4];
            #pragma unroll
            for (int qg = 0; qg < 2; ++qg)
                #pragma unroll
                for (int jn = 0; jn < 4; ++jn)
                    st[qg][jn] = (f32x4){ -16.f, -16.f, -16.f, -16.f };
            #pragma unroll
            for (int jn = 0; jn < 4; ++jn) {
                #pragma unroll
                for (int kk = 0; kk < 2; ++kk) {
                    short8 kf = *(const short8*)&Ks[kk][jn * 16 + lm][(lk ^ fr) * 8];
                    #pragma unroll
                    for (int qg = 0; qg < 2; ++qg)
                        st[qg][jn] = __builtin_amdgcn_mfma_f32_16x16x32_bf16(kf, qf[qg][kk], st[qg][jn], 0, 0, 0);
                }
            }

            // p = exp2(s - 16); pack to wave-private LDS (swizzled b64).
            #pragma unroll
            for (int qg = 0; qg < 2; ++qg)
                #pragma unroll
                for (int jn = 0; jn < 4; ++jn) {
                    const int cc = ((jn * 2 + (lk >> 1)) ^ sw) * 8 + (lk & 1) * 4;
                    pack4_store(&Pt[wq][qg][lm][cc],
                                exp2f(st[qg][jn][0]), exp2f(st[qg][jn][1]),
                                exp2f(st[qg][jn][2]), exp2f(st[qg][jn][3]));
                }

            short8 pf[2][2];
            #pragma unroll
            for (int qg = 0; qg < 2; ++qg) {
                pf[qg][0] = *(const short8*)&Pt[wq][qg][lm][((lk + 0) ^ sw) * 8];
                pf[qg][1] = *(const short8*)&Pt[wq][qg][lm][((lk + 4) ^ sw) * 8];
            }

            // l += ones-row MFMA (all rows = sum over keys): 4 MFMA.
            #pragma unroll
            for (int qg = 0; qg < 2; ++qg)
                #pragma unroll
                for (int kk = 0; kk < 2; ++kk)
                    lacc[qg] = __builtin_amdgcn_mfma_f32_16x16x32_bf16(ones, pf[qg][kk], lacc[qg], 0, 0, 0);

            // O^T += V^T P^T : 16 MFMA (no rescale needed).
            #pragma unroll
            for (int jd = 0; jd < 4; ++jd) {
                #pragma unroll
                for (int kk = 0; kk < 2; ++kk) {
                    short8 vf = *(const short8*)&Vs[kk][jd * 16 + lm][(lk ^ fr) * 8];
                    #pragma unroll
                    for (int qg = 0; qg < 2; ++qg)
                        O[qg][jd] = __builtin_amdgcn_mfma_f32_16x16x32_bf16(vf, pf[qg][kk], O[qg][jd], 0, 0, 0);
                }
            }
        }

        // epilogue: unnormalized O (bf16) + l (fp32) per query.
        #pragma unroll
        for (int qg = 0; qg < 2; ++qg) {
            const int q = q0 + qg * 16 + lm;
            unsigned short* orow = opart + ((((size_t)split * Bz + b) * NH + h) * S + q) * 64;
            #pragma unroll
            for (int jd = 0; jd < 4; ++jd)
                pack4_store(orow + jd * 16 + lk * 4,
                            O[qg][jd][0], O[qg][jd][1], O[qg][jd][2], O[qg][jd][3]);
            if (lk == 0)
                lbuf[(((size_t)split * Bz + b) * NH + h) * S + q] = lacc[qg][0];
        }
        return;
    }

    // =================== block-local path ===================
    // One wave per (b, 16-query block, head). Reuses Pt's first 4 KB.
    unsigned short (*PtL)[16][32] = (unsigned short(*)[16][32])&Pt[0][0][0][0];
    const unsigned short* qkvl = qkv + 3072;
    const int gid = (blockIdx.x - 1024) * 4 + wq;   // b*2048 + sub*16 + h
    const int h   = gid & 15;
    const int sub = (gid >> 4) & 127;
    const int b   = gid >> 11;
    const int s0  = sub * 16;

    // ---- QK^T (K rows as A, Q rows as B; both lane-row = lm).
    const unsigned short* base = qkvl + ((size_t)(b * S) + s0 + lm) * QS;
    f32x4 st = {};
    #pragma unroll
    for (int kk = 0; kk < 2; ++kk) {
        short8 kf = *(const short8*)(base + E + h * 64 + kk * 32 + lk * 8);
        short8 qf = *(const short8*)(base +     h * 64 + kk * 32 + lk * 8);
        st = __builtin_amdgcn_mfma_f32_16x16x32_bf16(kf, qf, st, 0, 0, 0);
    }

    // ---- softmax over 16 keys (4 in-lane + 2 shfl hops across lk).
    constexpr float SC = 0.125f * 1.44269504088896340736f;   // dh^-0.5 * log2(e)
    float tt[4];
    #pragma unroll
    for (int r = 0; r < 4; ++r) tt[r] = st[r] * SC;
    float mx = fmaxf(fmaxf(tt[0], tt[1]), fmaxf(tt[2], tt[3]));
    mx = fmaxf(mx, __shfl_xor(mx, 16, 64));
    mx = fmaxf(mx, __shfl_xor(mx, 32, 64));
    float p[4], l = 0.f;
    #pragma unroll
    for (int r = 0; r < 4; ++r) { p[r] = exp2f(tt[r] - mx); l += p[r]; }
    l += __shfl_xor(l, 16, 64);
    l += __shfl_xor(l, 32, 64);
    const float inv = 1.0f / l;

    // ---- pack P^T to wave-private LDS (zero-padded to K=32).
    pack4_store(&PtL[wq][lm][lk * 4], p[0], p[1], p[2], p[3]);
    pack4_store(&PtL[wq][lm][16 + lk * 4], 0.f, 0.f, 0.f, 0.f);
    short8 pf = *(const short8*)&PtL[wq][lm][lk * 8];

    // ---- PV: O^T = V^T P^T (4 MFMA over d-blocks).
    const unsigned short* vrow =
        vtl + (((size_t)(b * NH + h) * 64) + lm) * S + s0 + (lk & 1) * 8;
    f32x4 zero = {};
    unsigned short* dst = attn + ((size_t)(b * S) + s0 + lm) * 2048 + 1024 + h * 64 + lk * 4;
    #pragma unroll
    for (int jd = 0; jd < 4; ++jd) {
        short8 vf = *(const short8*)(vrow + (size_t)jd * 16 * S);
        f32x4 O = __builtin_amdgcn_mfma_f32_16x16x32_bf16(vf, pf, zero, 0, 0, 0);
        pack4_store(dst + jd * 16, O[0] * inv, O[1] * inv, O[2] * inv, O[3] * inv);
    }
}

// ---------------------------------------------------------------------------
// Merge NSPLIT=2 partials (shared fixed max): out = (o0+o1) / (l0+l1).
// Writes attn_cat global half (cols h*64, row stride 2048). Memory-bound.
// ---------------------------------------------------------------------------
__global__ __launch_bounds__(256)
void attn_merge(const unsigned short* __restrict__ opart, const float* __restrict__ lbuf,
                unsigned short* __restrict__ attn)
{
    const int id = blockIdx.x * 256 + threadIdx.x;   // B*NH*S*8 = 524288
    const int d8 = id & 7;
    const int q  = (id >> 3) & (S - 1);
    const int h  = (id >> 14) & 15;
    const int b  = id >> 18;

    const size_t base0 = (((size_t)0 * Bz + b) * NH + h) * S + q;
    const size_t base1 = (((size_t)1 * Bz + b) * NH + h) * S + q;
    const float inv = 1.0f / (lbuf[base0] + lbuf[base1]);

    bf16x8 o0 = *(const bf16x8*)(opart + base0 * 64 + d8 * 8);
    bf16x8 o1 = *(const bf16x8*)(opart + base1 * 64 + d8 * 8);
    unsigned short* dst = attn + ((size_t)(b * S) + q) * 2048 + h * 64 + d8 * 8;
    #pragma unroll
    for (int j = 0; j < 8; j += 4)
        pack4_store(dst + j,
                    (bf2f(o0[j+0]) + bf2f(o1[j+0])) * inv,
                    (bf2f(o0[j+1]) + bf2f(o1[j+1])) * inv,
                    (bf2f(o0[j+2]) + bf2f(o1[j+2])) * inv,
                    (bf2f(o0[j+3]) + bf2f(o1[j+3])) * inv);
}

// ---------------------------------------------------------------------------
extern "C" void kernel_launch(void* const* d_in, const int* in_sizes, int n_in,
                              void* d_out, int out_size, void* d_ws, size_t ws_size,
                              hipStream_t stream)
{
    const float* x       = (const float*)d_in[0];
    const float* w_in_g  = (const float*)d_in[1];
    const float* b_in_g  = (const float*)d_in[2];
    const float* w_out_g = (const float*)d_in[3];
    const float* b_out_g = (const float*)d_in[4];
    const float* w_in_l  = (const float*)d_in[5];
    const float* b_in_l  = (const float*)d_in[6];
    const float* w_out_l = (const float*)d_in[7];
    const float* b_out_l = (const float*)d_in[8];
    const float* w_f     = (const float*)d_in[9];
    const float* b_f     = (const float*)d_in[10];
    float* out = (float*)d_out;

    const int M = Bz * S;   // 4096
    char* p = (char*)d_ws;
    unsigned short* xb       = (unsigned short*)p; p += (size_t)M * 1024 * 2;        //  8 MB
    unsigned short* qkv_all  = (unsigned short*)p; p += (size_t)M * QS * 2;          // 48 MB
    unsigned short* attn_cat = (unsigned short*)p; p += (size_t)M * 2048 * 2;        // 16 MB
    unsigned short* win_all  = (unsigned short*)p; p += (size_t)6144 * 1024 * 2;     // 12 MB
    unsigned short* wf_b     = (unsigned short*)p; p += (size_t)1024 * 2048 * 2;     //  4 MB
    unsigned short* woutT    = (unsigned short*)p; p += (size_t)2 * 1024 * 1024 * 2; //  4 MB
    unsigned short* wcomb    = (unsigned short*)p; p += (size_t)1024 * 2048 * 2;     //  4 MB
    unsigned short* vtbuf    = (unsigned short*)p; p += (size_t)Bz * NH * 64 * S * 2;//  8 MB
    unsigned short* vtlbuf   = (unsigned short*)p; p += (size_t)Bz * NH * 64 * S * 2;//  8 MB
    unsigned short* opart    = (unsigned short*)p; p += (size_t)NSPLIT * Bz * NH * S * 64 * 2; // 16.8 MB
    float*          lbuf     = (float*)p;          p += (size_t)NSPLIT * Bz * NH * S * 4;      // 0.5 MB
    float*          cb       = (float*)p;          p += 1024 * 4;

    dim3 blk(256);

    // 1) all preprocessing in one launch.
    PrepArgs pa;
    pa.csrc[0] = x;      pa.cdst[0] = xb;                    pa.cn[0] = M * 1024;
    pa.csrc[1] = w_in_g; pa.cdst[1] = win_all;               pa.cn[1] = 3072 * 1024;
    pa.csrc[2] = w_in_l; pa.cdst[2] = win_all + 3072 * 1024; pa.cn[2] = 3072 * 1024;
    pa.csrc[3] = w_f;    pa.cdst[3] = wf_b;                  pa.cn[3] = 1024 * 2048;
    pa.wog = w_out_g; pa.wol = w_out_l;
    pa.wogT = woutT;  pa.wolT = woutT + 1024 * 1024;
    pa.wf = w_f; pa.bf = b_f; pa.bog = b_out_g; pa.bol = b_out_l; pa.cb = cb;
    prep_all<<<dim3(13056), blk, 0, stream>>>(pa);

    // 2) QKV GEMM + wcomb GEMM in ONE launch (1536 + 128 blocks).
    GemmFusedArgs ga;
    ga.xb = xb;  ga.win = win_all;  ga.wfb = wf_b;  ga.woutT = woutT;
    ga.bg = b_in_g;  ga.bl = b_in_l;
    ga.qkv = qkv_all;  ga.vt = vtbuf;  ga.vtl = vtlbuf;  ga.wcomb = wcomb;
    gemm_fused<<<dim3(1664), blk, 0, stream>>>(ga);

    // 3) global flash (NSPLIT=2 split-K, 1024 blocks) + local attention.
    attn_fused<<<dim3(2048), blk, 0, stream>>>(
        qkv_all, vtbuf, vtlbuf, opart, lbuf, attn_cat);

    // 4) merge split-K partials into attn_cat global half.
    attn_merge<<<dim3(Bz * NH * S * 8 / 256), blk, 0, stream>>>(opart, lbuf, attn_cat);

    // 5) Fused tail: out = attn_cat [4096,2048] @ wcomb[1024,2048]^T + cb (fp32).
    gemm_tail<<<dim3(1024 / 64, M / 128), blk, 0, stream>>>(
        attn_cat, wcomb, cb, out);
}

// Round 12
// 292.227 us; speedup vs baseline: 1.0392x; 1.0032x over previous
//
#include <hip/hip_runtime.h>
#include <hip/hip_bf16.h>
#include <math.h>
#include <stdint.h>

// Problem constants (fixed by the reference).
constexpr int Bz = 2;
constexpr int S  = 2048;
constexpr int E  = 1024;
constexpr int NH = 16;
constexpr int DH = 64;
constexpr int QS = 6144;        // combined qkv row stride: [g q|k|v | l q|k|v]

typedef __attribute__((ext_vector_type(8))) short short8;      // MFMA A/B frag (8 bf16)
typedef __attribute__((ext_vector_type(4))) float f32x4;       // MFMA C/D frag
typedef __attribute__((ext_vector_type(8))) unsigned short bf16x8;
typedef __attribute__((ext_vector_type(4))) unsigned short bf16x4;

__device__ __forceinline__ float bf2f(unsigned short u) {
    union { unsigned int i; float f; } c; c.i = ((unsigned int)u) << 16; return c.f;
}
__device__ __forceinline__ unsigned short f2bf(float f) {   // round-to-nearest-even
    union { float f; unsigned int i; } c; c.f = f;
    unsigned int r = c.i + 0x7fffu + ((c.i >> 16) & 1u);
    return (unsigned short)(r >> 16);
}

// 4x f32 -> packed bf16x4 store (hot path: HW pack if available).
__device__ __forceinline__ void pack4_store(unsigned short* dst,
                                            float a, float b, float c, float d) {
#if __has_builtin(__builtin_amdgcn_cvt_pk_bf16_f32)
    auto p0 = __builtin_amdgcn_cvt_pk_bf16_f32(a, b);
    auto p1 = __builtin_amdgcn_cvt_pk_bf16_f32(c, d);
    union { decltype(p0) v; unsigned int u; } c0, c1;
    c0.v = p0; c1.v = p1;
    uint2 w; w.x = c0.u; w.y = c1.u;
    *(uint2*)dst = w;
#else
    bf16x4 o = { f2bf(a), f2bf(b), f2bf(c), f2bf(d) };
    *(bf16x4*)dst = o;
#endif
}

#define GLD_LDS(g, l) __builtin_amdgcn_global_load_lds( \
    (const __attribute__((address_space(1))) void*)(g), \
    (__attribute__((address_space(3))) void*)(l), 16, 0, 0)

// ---------------------------------------------------------------------------
// prep_all — one launch for all preprocessing:
//   blocks [0, 12288)      : fp32->bf16 cvt of {x, w_in_g, w_in_l, w_f}
//   blocks [12288, 12800)  : transpose-convert w_out_g/l -> bf16 woutT
//   blocks [12800, 13056)  : cb[n] = b_f + wf[:, :1024]@bog + wf[:, 1024:]@bol
// ---------------------------------------------------------------------------
struct PrepArgs {
    const float* csrc[4]; unsigned short* cdst[4]; int cn[4];
    const float* wog; const float* wol;
    unsigned short* wogT; unsigned short* wolT;
    const float* wf; const float* bf; const float* bog; const float* bol;
    float* cb;
};

__global__ __launch_bounds__(256)
void prep_all(PrepArgs a)
{
    __shared__ unsigned short T[64][72];
    const int bid = blockIdx.x, t = threadIdx.x;

    if (bid < 12288) {                      // ---- cvt path
        int i = (bid * 256 + t) * 4;
        #pragma unroll
        for (int r = 0; r < 4; ++r) {
            if (i < a.cn[r]) {
                float4 v = *(const float4*)(a.csrc[r] + i);
                bf16x4 o = { f2bf(v.x), f2bf(v.y), f2bf(v.z), f2bf(v.w) };
                *(bf16x4*)(a.cdst[r] + i) = o;
                return;
            }
            i -= a.cn[r];
        }
        return;
    }
    if (bid < 12800) {                      // ---- transpose-convert path
        const int id = bid - 12288;
        const int tj = id & 15, ti = (id >> 4) & 15, mat = id >> 8;
        const float* src = mat ? a.wol : a.wog;
        unsigned short* dst = mat ? a.wolT : a.wogT;
        #pragma unroll
        for (int r = 0; r < 4; ++r) {
            const int c = r * 256 + t;
            const int row = c >> 4, col4 = (c & 15) * 4;
            float4 v = *(const float4*)(src + (size_t)(ti * 64 + row) * 1024 + tj * 64 + col4);
            T[col4 + 0][row] = f2bf(v.x);
            T[col4 + 1][row] = f2bf(v.y);
            T[col4 + 2][row] = f2bf(v.z);
            T[col4 + 3][row] = f2bf(v.w);
        }
        __syncthreads();
        #pragma unroll
        for (int r = 0; r < 2; ++r) {
            const int c = r * 256 + t;
            const int jrow = c >> 3, ig = (c & 7) * 8;
            bf16x8 o;
            #pragma unroll
            for (int k = 0; k < 8; ++k) o[k] = T[jrow][ig + k];
            *(bf16x8*)(dst + (size_t)(tj * 64 + jrow) * 1024 + ti * 64 + ig) = o;
        }
        return;
    }
    {                                       // ---- combined-bias path
        const int lane = t & 63;
        const int n = (bid - 12800) * 4 + (t >> 6);
        const float* row = a.wf + (size_t)n * 2048;
        float s = 0.f;
        #pragma unroll
        for (int i = 0; i < 16; ++i) s = fmaf(row[i * 64 + lane], a.bog[i * 64 + lane], s);
        #pragma unroll
        for (int i = 16; i < 32; ++i) s = fmaf(row[i * 64 + lane], a.bol[i * 64 + lane - 1024], s);
        #pragma unroll
        for (int off = 32; off > 0; off >>= 1) s += __shfl_xor(s, off, 64);
        if (lane == 0) a.cb[n] = a.bf[n] + s;
    }
}

// ---------------------------------------------------------------------------
// gemm_fused — one launch for BOTH K=1024 GEMMs:
//   blocks [0, 1536)   : QKV  [4096,6144] = xb @ win_all^T (+bias, +fused
//                        V-transposes)  — bk64 128x128.
//   blocks [1536,1664) : wcomb_z [1024,1024@z] = wf_b[:,z*1024:] @ woutT_z^T.
// V-range columns of qkv (nn in [2048,3072) u [5120,6144)) are dead in C
// (read via vt/vtl only) — C stores skipped.
// ---------------------------------------------------------------------------
struct GemmFusedArgs {
    const unsigned short* xb;    const unsigned short* win;
    const unsigned short* wfb;   const unsigned short* woutT;
    const float* bg;             const float* bl;
    unsigned short* qkv;  unsigned short* vt;  unsigned short* vtl;
    unsigned short* wcomb;
};

__global__ __launch_bounds__(256, 2)
void gemm_fused(GemmFusedArgs g)
{
    __shared__ __align__(16) short As[128 * 64];   // 16 KB
    __shared__ __align__(16) short Bs[128 * 64];   // 16 KB

    const int bid = blockIdx.x;
    const unsigned short *A, *W;
    unsigned short *C, *vt, *vtl;
    const float *bias0, *bias1;
    int m0, n0, lda, ldw, ldc, nsplit;

    if (bid < 1536) {                       // ---- QKV branch
        m0 = (bid / 48) * 128;  n0 = (bid % 48) * 128;
        A = g.xb;  W = g.win;  C = g.qkv;  vt = g.vt;  vtl = g.vtl;
        bias0 = g.bg;  bias1 = g.bl;
        lda = 1024;  ldw = 1024;  ldc = QS;  nsplit = 3072;
    } else {                                // ---- wcomb branch
        const int id = bid - 1536;
        const int z = id >> 6;
        m0 = ((id >> 3) & 7) * 128;  n0 = (id & 7) * 128;
        A = g.wfb + z * 1024;
        W = g.woutT + (size_t)z * 1024 * 1024;
        C = g.wcomb + z * 1024;
        vt = nullptr;  vtl = nullptr;  bias0 = nullptr;  bias1 = nullptr;
        lda = 2048;  ldw = 1024;  ldc = 2048;  nsplit = 0;
    }

    const int t = threadIdx.x;
    const int lane = t & 63, wave = t >> 6;
    const int wm = wave & 1, wn = wave >> 1;
    const int lm = lane & 15, lk = lane >> 4;

    f32x4 acc[4][4] = {};

    const int row0 = t >> 3, kg0 = (t & 7) * 8;
    const unsigned short* a0 = A + (size_t)(m0 + row0) * lda + kg0;
    const unsigned short* w0 = W + (size_t)(n0 + row0) * ldw + kg0;

    for (int k0 = 0; k0 < 1024; k0 += 64) {
        __syncthreads();
        #pragma unroll
        for (int r = 0; r < 4; ++r)
            GLD_LDS(a0 + (size_t)(r * 32) * lda + k0, As + ((size_t)(r * 256 + wave * 64)) * 8);
        #pragma unroll
        for (int r = 0; r < 4; ++r)
            GLD_LDS(w0 + (size_t)(r * 32) * ldw + k0, Bs + ((size_t)(r * 256 + wave * 64)) * 8);
        __syncthreads();

        #pragma unroll
        for (int ks = 0; ks < 2; ++ks) {
            short8 af[4], bfr[4];
            #pragma unroll
            for (int i = 0; i < 4; ++i)
                af[i] = *(const short8*)&As[(wm * 64 + i * 16 + lm) * 64 + ks * 32 + lk * 8];
            #pragma unroll
            for (int j = 0; j < 4; ++j)
                bfr[j] = *(const short8*)&Bs[(wn * 64 + j * 16 + lm) * 64 + ks * 32 + lk * 8];
            #pragma unroll
            for (int i = 0; i < 4; ++i)
                #pragma unroll
                for (int j = 0; j < 4; ++j)
                    acc[i][j] = __builtin_amdgcn_mfma_f32_16x16x32_bf16(af[i], bfr[j], acc[i][j], 0, 0, 0);
        }
    }

    #pragma unroll
    for (int i = 0; i < 4; ++i) {
        #pragma unroll
        for (int j = 0; j < 4; ++j) {
            const int nn = n0 + wn * 64 + j * 16 + lm;
            const float bv = (nn < nsplit) ? (bias0 ? bias0[nn] : 0.f)
                                           : (bias1 ? bias1[nn - nsplit] : 0.f);
            const int mm0 = m0 + wm * 64 + i * 16 + lk * 4;
            float vv[4];
            // V columns are dead in C (read via vt/vtl only) — skip the store.
            const bool deadC = vt && ((nn >= 2048 && nn < 3072) || nn >= 5120);
            #pragma unroll
            for (int r = 0; r < 4; ++r) {
                vv[r] = acc[i][j][r] + bv;
                if (!deadC) C[(size_t)(mm0 + r) * ldc + nn] = f2bf(vv[r]);
            }
            if (vt) {
                const int nl = nn - 2048;              // V-range of global half
                if (nl >= 0 && nl < 1024) {
                    const int hh = nl >> 6, dd = nl & 63;
                    const int bb = mm0 >> 11, ss = mm0 & 2047;
                    pack4_store(vt + ((size_t)(bb * NH + hh) * 64 + dd) * S + ss,
                                vv[0], vv[1], vv[2], vv[3]);
                }
                const int nl2 = nn - 5120;             // V-range of local half
                if (nl2 >= 0) {
                    const int hh = nl2 >> 6, dd = nl2 & 63;
                    const int bb = mm0 >> 11, ss = mm0 & 2047;
                    pack4_store(vtl + ((size_t)(bb * NH + hh) * 64 + dd) * S + ss,
                                vv[0], vv[1], vv[2], vv[3]);
                }
            }
        }
    }
}

// ---------------------------------------------------------------------------
// gemm_tail — 128x64 tile, BK=64 (tail: [4096,1024] = attn_cat @ wcomb^T + cb,
// fp32 out). 512 blocks at 2/CU = one full round.
// ---------------------------------------------------------------------------
__global__ __launch_bounds__(256, 2)
void gemm_tail(const unsigned short* __restrict__ A, const unsigned short* __restrict__ W,
               const float* __restrict__ bias, float* __restrict__ C)
{
    __shared__ __align__(16) short As[128 * 64];   // 16 KB
    __shared__ __align__(16) short Bs[64 * 64];    //  8 KB

    const int t = threadIdx.x;
    const int lane = t & 63, wave = t >> 6;
    const int wm = wave & 1, wn = wave >> 1;       // 2M x 2N wave grid
    const int m0 = blockIdx.y * 128, n0 = blockIdx.x * 64;
    const int lm = lane & 15, lk = lane >> 4;

    f32x4 acc[4][2] = {};

    const int row0 = t >> 3, kg0 = (t & 7) * 8;
    const unsigned short* a0 = A + (size_t)(m0 + row0) * 2048 + kg0;
    const unsigned short* w0 = W + (size_t)(n0 + row0) * 2048 + kg0;

    for (int k0 = 0; k0 < 2048; k0 += 64) {
        __syncthreads();
        #pragma unroll
        for (int r = 0; r < 4; ++r)
            GLD_LDS(a0 + (size_t)(r * 32) * 2048 + k0, As + ((size_t)(r * 256 + wave * 64)) * 8);
        #pragma unroll
        for (int r = 0; r < 2; ++r)
            GLD_LDS(w0 + (size_t)(r * 32) * 2048 + k0, Bs + ((size_t)(r * 256 + wave * 64)) * 8);
        __syncthreads();

        #pragma unroll
        for (int ks = 0; ks < 2; ++ks) {
            short8 af[4], bfr[2];
            #pragma unroll
            for (int i = 0; i < 4; ++i)
                af[i] = *(const short8*)&As[(wm * 64 + i * 16 + lm) * 64 + ks * 32 + lk * 8];
            #pragma unroll
            for (int j = 0; j < 2; ++j)
                bfr[j] = *(const short8*)&Bs[(wn * 32 + j * 16 + lm) * 64 + ks * 32 + lk * 8];
            #pragma unroll
            for (int i = 0; i < 4; ++i)
                #pragma unroll
                for (int j = 0; j < 2; ++j)
                    acc[i][j] = __builtin_amdgcn_mfma_f32_16x16x32_bf16(af[i], bfr[j], acc[i][j], 0, 0, 0);
        }
    }

    #pragma unroll
    for (int i = 0; i < 4; ++i) {
        #pragma unroll
        for (int j = 0; j < 2; ++j) {
            const int nn = n0 + wn * 32 + j * 16 + lm;
            const float bv = bias[nn];
            const int mm0 = m0 + wm * 64 + i * 16 + lk * 4;
            #pragma unroll
            for (int r = 0; r < 4; ++r)
                C[(size_t)(mm0 + r) * 1024 + nn] = acc[i][j][r] + bv;
        }
    }
}

// ---------------------------------------------------------------------------
// attn_fused — one launch for both attention flavors (empirical-best config,
// reproduces the 291.2 us measurement):
//   blocks [0, 512)    : global flash attention, NSPLIT=1, XCD-chunked remap
//                        (xcd = bid&7 owns 4 (b,h) pairs), 2 barriers/iter,
//                        direct normalized write to attn_cat.
//   blocks [512, 1536) : block-local MFMA attention (writes local half).
// ---------------------------------------------------------------------------
__global__ __launch_bounds__(256, 2)
void attn_fused(const unsigned short* __restrict__ qkv,
                const unsigned short* __restrict__ vt,
                const unsigned short* __restrict__ vtl,
                unsigned short* __restrict__ attn)
{
    __shared__ __align__(16) unsigned short Ks[2][64][32];    // 8 KB
    __shared__ __align__(16) unsigned short Vs[2][64][32];    // 8 KB
    __shared__ __align__(16) unsigned short Pt[4][2][16][64]; // 16 KB

    const int t = threadIdx.x, lane = t & 63, wq = t >> 6;
    const int lm = lane & 15, lk = lane >> 4;

    if (blockIdx.x < 512) {
        // =================== global flash path ===================
        // XCD-chunked decode: xcd = bid&7, slot = bid>>3;
        // pair p = xcd*4 + slot/16 (b=p>>4, h=p&15), qb = slot%16. Bijective.
        const int bid = blockIdx.x;
        const int slot = bid >> 3;
        const int p  = (bid & 7) * 4 + (slot >> 4);
        const int qb = slot & 15;
        const int h  = p & 15;
        const int b  = p >> 4;
        const int q0 = qb * 128 + wq * 32;   // wave's first query

        constexpr float QSCALE = 0.125f * 1.44269504088896340736f;
        short8 qf[2][2];
        #pragma unroll
        for (int qg = 0; qg < 2; ++qg) {
            const unsigned short* qrow = qkv + ((size_t)(b * S) + q0 + qg * 16 + lm) * QS + h * DH;
            #pragma unroll
            for (int kk = 0; kk < 2; ++kk) {
                bf16x8 v = *(const bf16x8*)(qrow + kk * 32 + lk * 8);
                #pragma unroll
                for (int j = 0; j < 8; ++j)
                    ((unsigned short*)&qf[qg][kk])[j] = f2bf(bf2f(v[j]) * QSCALE);
            }
        }

        short8 ones;                          // bf16 1.0 per element
        #pragma unroll
        for (int j = 0; j < 8; ++j) ((unsigned short*)&ones)[j] = 0x3F80;

        const int row0 = t >> 2;
        const int sw0 = (row0 ^ (row0 >> 2)) & 3;
        const int g0 = ((t & 3) ^ sw0) * 8;
        const unsigned short* kg[2];
        const unsigned short* vg[2];
        #pragma unroll
        for (int r = 0; r < 2; ++r) {
            kg[r] = qkv + ((size_t)(b * S) + row0) * QS + E + h * 64 + r * 32 + g0;
            vg[r] = vt + ((size_t)(b * NH + h) * 64 + row0) * S + r * 32 + g0;
        }
        unsigned short* kl[2] = { &Ks[0][0][0] + (wq * 64) * 8, &Ks[0][0][0] + (256 + wq * 64) * 8 };
        unsigned short* vl[2] = { &Vs[0][0][0] + (wq * 64) * 8, &Vs[0][0][0] + (256 + wq * 64) * 8 };

        f32x4 O[2][4] = {};
        f32x4 lacc[2] = {};
        const int sw = lm & 7;
        const int fr = (lm ^ (lm >> 2)) & 3;

        for (int kt = 0; kt < 32; ++kt) {
            __syncthreads();
            GLD_LDS(kg[0] + (size_t)kt * 64 * QS, kl[0]);
            GLD_LDS(kg[1] + (size_t)kt * 64 * QS, kl[1]);
            GLD_LDS(vg[0] + kt * 64, vl[0]);
            GLD_LDS(vg[1] + kt * 64, vl[1]);
            __syncthreads();

            // S^T = K Q^T - 16 (fixed-max shift via C-init): 16 MFMA.
            f32x4 st[2][4];
            #pragma unroll
            for (int qg = 0; qg < 2; ++qg)
                #pragma unroll
                for (int jn = 0; jn < 4; ++jn)
                    st[qg][jn] = (f32x4){ -16.f, -16.f, -16.f, -16.f };
            #pragma unroll
            for (int jn = 0; jn < 4; ++jn) {
                #pragma unroll
                for (int kk = 0; kk < 2; ++kk) {
                    short8 kf = *(const short8*)&Ks[kk][jn * 16 + lm][(lk ^ fr) * 8];
                    #pragma unroll
                    for (int qg = 0; qg < 2; ++qg)
                        st[qg][jn] = __builtin_amdgcn_mfma_f32_16x16x32_bf16(kf, qf[qg][kk], st[qg][jn], 0, 0, 0);
                }
            }

            // p = exp2(s - 16); pack to wave-private LDS (swizzled b64).
            #pragma unroll
            for (int qg = 0; qg < 2; ++qg)
                #pragma unroll
                for (int jn = 0; jn < 4; ++jn) {
                    const int cc = ((jn * 2 + (lk >> 1)) ^ sw) * 8 + (lk & 1) * 4;
                    pack4_store(&Pt[wq][qg][lm][cc],
                                exp2f(st[qg][jn][0]), exp2f(st[qg][jn][1]),
                                exp2f(st[qg][jn][2]), exp2f(st[qg][jn][3]));
                }

            short8 pf[2][2];
            #pragma unroll
            for (int qg = 0; qg < 2; ++qg) {
                pf[qg][0] = *(const short8*)&Pt[wq][qg][lm][((lk + 0) ^ sw) * 8];
                pf[qg][1] = *(const short8*)&Pt[wq][qg][lm][((lk + 4) ^ sw) * 8];
            }

            // l += ones-row MFMA (all rows = sum over keys): 4 MFMA.
            #pragma unroll
            for (int qg = 0; qg < 2; ++qg)
                #pragma unroll
                for (int kk = 0; kk < 2; ++kk)
                    lacc[qg] = __builtin_amdgcn_mfma_f32_16x16x32_bf16(ones, pf[qg][kk], lacc[qg], 0, 0, 0);

            // O^T += V^T P^T : 16 MFMA (no rescale needed).
            #pragma unroll
            for (int jd = 0; jd < 4; ++jd) {
                #pragma unroll
                for (int kk = 0; kk < 2; ++kk) {
                    short8 vf = *(const short8*)&Vs[kk][jd * 16 + lm][(lk ^ fr) * 8];
                    #pragma unroll
                    for (int qg = 0; qg < 2; ++qg)
                        O[qg][jd] = __builtin_amdgcn_mfma_f32_16x16x32_bf16(vf, pf[qg][kk], O[qg][jd], 0, 0, 0);
                }
            }
        }

        // epilogue: normalized O directly to attn_cat global half.
        #pragma unroll
        for (int qg = 0; qg < 2; ++qg) {
            const int q = q0 + qg * 16 + lm;
            const float inv = 1.0f / lacc[qg][0];
            unsigned short* dst = attn + ((size_t)(b * S) + q) * 2048 + h * 64 + lk * 4;
            #pragma unroll
            for (int jd = 0; jd < 4; ++jd)
                pack4_store(dst + jd * 16,
                            O[qg][jd][0] * inv, O[qg][jd][1] * inv,
                            O[qg][jd][2] * inv, O[qg][jd][3] * inv);
        }
        return;
    }

    // =================== block-local path ===================
    // One wave per (b, 16-query block, head). Reuses Pt's first 4 KB.
    unsigned short (*PtL)[16][32] = (unsigned short(*)[16][32])&Pt[0][0][0][0];
    const unsigned short* qkvl = qkv + 3072;
    const int gid = (blockIdx.x - 512) * 4 + wq;   // b*2048 + sub*16 + h
    const int h   = gid & 15;
    const int sub = (gid >> 4) & 127;
    const int b   = gid >> 11;
    const int s0  = sub * 16;

    // ---- QK^T (K rows as A, Q rows as B; both lane-row = lm).
    const unsigned short* base = qkvl + ((size_t)(b * S) + s0 + lm) * QS;
    f32x4 st = {};
    #pragma unroll
    for (int kk = 0; kk < 2; ++kk) {
        short8 kf = *(const short8*)(base + E + h * 64 + kk * 32 + lk * 8);
        short8 qf = *(const short8*)(base +     h * 64 + kk * 32 + lk * 8);
        st = __builtin_amdgcn_mfma_f32_16x16x32_bf16(kf, qf, st, 0, 0, 0);
    }

    // ---- softmax over 16 keys (4 in-lane + 2 shfl hops across lk).
    constexpr float SC = 0.125f * 1.44269504088896340736f;   // dh^-0.5 * log2(e)
    float tt[4];
    #pragma unroll
    for (int r = 0; r < 4; ++r) tt[r] = st[r] * SC;
    float mx = fmaxf(fmaxf(tt[0], tt[1]), fmaxf(tt[2], tt[3]));
    mx = fmaxf(mx, __shfl_xor(mx, 16, 64));
    mx = fmaxf(mx, __shfl_xor(mx, 32, 64));
    float p[4], l = 0.f;
    #pragma unroll
    for (int r = 0; r < 4; ++r) { p[r] = exp2f(tt[r] - mx); l += p[r]; }
    l += __shfl_xor(l, 16, 64);
    l += __shfl_xor(l, 32, 64);
    const float inv = 1.0f / l;

    // ---- pack P^T to wave-private LDS (zero-padded to K=32).
    pack4_store(&PtL[wq][lm][lk * 4], p[0], p[1], p[2], p[3]);
    pack4_store(&PtL[wq][lm][16 + lk * 4], 0.f, 0.f, 0.f, 0.f);
    short8 pf = *(const short8*)&PtL[wq][lm][lk * 8];

    // ---- PV: O^T = V^T P^T (4 MFMA over d-blocks).
    const unsigned short* vrow =
        vtl + (((size_t)(b * NH + h) * 64) + lm) * S + s0 + (lk & 1) * 8;
    f32x4 zero = {};
    unsigned short* dst = attn + ((size_t)(b * S) + s0 + lm) * 2048 + 1024 + h * 64 + lk * 4;
    #pragma unroll
    for (int jd = 0; jd < 4; ++jd) {
        short8 vf = *(const short8*)(vrow + (size_t)jd * 16 * S);
        f32x4 O = __builtin_amdgcn_mfma_f32_16x16x32_bf16(vf, pf, zero, 0, 0, 0);
        pack4_store(dst + jd * 16, O[0] * inv, O[1] * inv, O[2] * inv, O[3] * inv);
    }
}

// ---------------------------------------------------------------------------
extern "C" void kernel_launch(void* const* d_in, const int* in_sizes, int n_in,
                              void* d_out, int out_size, void* d_ws, size_t ws_size,
                              hipStream_t stream)
{
    const float* x       = (const float*)d_in[0];
    const float* w_in_g  = (const float*)d_in[1];
    const float* b_in_g  = (const float*)d_in[2];
    const float* w_out_g = (const float*)d_in[3];
    const float* b_out_g = (const float*)d_in[4];
    const float* w_in_l  = (const float*)d_in[5];
    const float* b_in_l  = (const float*)d_in[6];
    const float* w_out_l = (const float*)d_in[7];
    const float* b_out_l = (const float*)d_in[8];
    const float* w_f     = (const float*)d_in[9];
    const float* b_f     = (const float*)d_in[10];
    float* out = (float*)d_out;

    const int M = Bz * S;   // 4096
    char* p = (char*)d_ws;
    unsigned short* xb       = (unsigned short*)p; p += (size_t)M * 1024 * 2;        //  8 MB
    unsigned short* qkv_all  = (unsigned short*)p; p += (size_t)M * QS * 2;          // 48 MB
    unsigned short* attn_cat = (unsigned short*)p; p += (size_t)M * 2048 * 2;        // 16 MB
    unsigned short* win_all  = (unsigned short*)p; p += (size_t)6144 * 1024 * 2;     // 12 MB
    unsigned short* wf_b     = (unsigned short*)p; p += (size_t)1024 * 2048 * 2;     //  4 MB
    unsigned short* woutT    = (unsigned short*)p; p += (size_t)2 * 1024 * 1024 * 2; //  4 MB
    unsigned short* wcomb    = (unsigned short*)p; p += (size_t)1024 * 2048 * 2;     //  4 MB
    unsigned short* vtbuf    = (unsigned short*)p; p += (size_t)Bz * NH * 64 * S * 2;//  8 MB
    unsigned short* vtlbuf   = (unsigned short*)p; p += (size_t)Bz * NH * 64 * S * 2;//  8 MB
    float*          cb       = (float*)p;          p += 1024 * 4;

    dim3 blk(256);

    // 1) all preprocessing in one launch.
    PrepArgs pa;
    pa.csrc[0] = x;      pa.cdst[0] = xb;                    pa.cn[0] = M * 1024;
    pa.csrc[1] = w_in_g; pa.cdst[1] = win_all;               pa.cn[1] = 3072 * 1024;
    pa.csrc[2] = w_in_l; pa.cdst[2] = win_all + 3072 * 1024; pa.cn[2] = 3072 * 1024;
    pa.csrc[3] = w_f;    pa.cdst[3] = wf_b;                  pa.cn[3] = 1024 * 2048;
    pa.wog = w_out_g; pa.wol = w_out_l;
    pa.wogT = woutT;  pa.wolT = woutT + 1024 * 1024;
    pa.wf = w_f; pa.bf = b_f; pa.bog = b_out_g; pa.bol = b_out_l; pa.cb = cb;
    prep_all<<<dim3(13056), blk, 0, stream>>>(pa);

    // 2) QKV GEMM + wcomb GEMM in ONE launch (1536 + 128 blocks).
    GemmFusedArgs ga;
    ga.xb = xb;  ga.win = win_all;  ga.wfb = wf_b;  ga.woutT = woutT;
    ga.bg = b_in_g;  ga.bl = b_in_l;
    ga.qkv = qkv_all;  ga.vt = vtbuf;  ga.vtl = vtlbuf;  ga.wcomb = wcomb;
    gemm_fused<<<dim3(1664), blk, 0, stream>>>(ga);

    // 3) global flash (XCD-chunked, NSPLIT=1) + local attention in ONE launch.
    attn_fused<<<dim3(1536), blk, 0, stream>>>(qkv_all, vtbuf, vtlbuf, attn_cat);

    // 4) Fused tail: out = attn_cat [4096,2048] @ wcomb[1024,2048]^T + cb (fp32).
    gemm_tail<<<dim3(1024 / 64, M / 128), blk, 0, stream>>>(
        attn_cat, wcomb, cb, out);
}